// Round 5
// baseline (1319.877 us; speedup 1.0000x reference)
//
#include <hip/hip_runtime.h>
#include <hip/hip_bf16.h>

#define B 32
#define N 4096
#define C 768
#define H 12
#define HD 64
// SCALE = 0.125f folded into qk

// kT: WkT[co][c] = Wk[c][co]
__global__ __launch_bounds__(256) void kT(const float* __restrict__ A, float* __restrict__ AT) {
    __shared__ float tile[32][33];
    int bx = blockIdx.x % 24, by = blockIdx.x / 24;
    int tx = threadIdx.x & 31, ty = threadIdx.x >> 5;   // ty 0..7
#pragma unroll
    for (int i = 0; i < 32; i += 8)
        tile[ty + i][tx] = A[(size_t)(by * 32 + ty + i) * C + bx * 32 + tx];
    __syncthreads();
#pragma unroll
    for (int i = 0; i < 32; i += 8)
        AT[(size_t)(bx * 32 + ty + i) * C + by * 32 + tx] = tile[tx][ty + i];
}

// K1: q[b,co] = sum_c x[b,0,c] * Wq[c,co]
__global__ __launch_bounds__(256) void k1_q(const float* __restrict__ x,
                                            const float* __restrict__ Wq,
                                            float* __restrict__ q) {
    __shared__ float xs[C];
    int b = blockIdx.x / 3;
    int coBase = (blockIdx.x % 3) * 256;
    int t = threadIdx.x;
    for (int i = t; i < C; i += 256) xs[i] = x[(size_t)b * N * C + i];
    __syncthreads();
    int co = coBase + t;
    float acc = 0.f;
    for (int c = 0; c < C; ++c) acc = fmaf(xs[c], Wq[(size_t)c * C + co], acc);
    q[b * C + co] = acc;
}

// K2: qk[b,h,c] = 0.125 * sum_d q[b,h*64+d] * WkT[h*64+d, c]; also zero xa
__global__ __launch_bounds__(256) void k2_qk(const float* __restrict__ q,
                                             const float* __restrict__ WkT,
                                             float* __restrict__ qk,
                                             float* __restrict__ xa) {
    int b = blockIdx.x / H, h = blockIdx.x % H;
    int t = threadIdx.x;
    __shared__ float qs[HD];
    if (t < HD) qs[t] = q[b * C + h * HD + t];
    float* xab = xa + ((size_t)b * H + h) * C;
    xab[t] = 0.f; xab[t + 256] = 0.f; xab[t + 512] = 0.f;
    __syncthreads();
    float a0 = 0.f, a1 = 0.f, a2 = 0.f;
    const float* wbase = WkT + (size_t)h * HD * C;
    for (int d = 0; d < HD; ++d) {
        float qd = qs[d];
        const float* wr = wbase + (size_t)d * C;
        a0 = fmaf(qd, wr[t], a0);
        a1 = fmaf(qd, wr[t + 256], a1);
        a2 = fmaf(qd, wr[t + 512], a2);
    }
    float* qkb = qk + ((size_t)b * H + h) * C;
    qkb[t] = a0 * 0.125f; qkb[t + 256] = a1 * 0.125f; qkb[t + 512] = a2 * 0.125f;
}

// K3: p2[b,h,n] = x[b,n,:] . qk[b,h,:]   (writes [B,H,N] layout)
__global__ __launch_bounds__(512) void k3_scores(const float* __restrict__ x,
                                                 const float* __restrict__ qk,
                                                 float* __restrict__ p2) {
    __shared__ float4 qks[H * 192];   // 36 KB
    int b = blockIdx.x >> 5;
    int chunk = blockIdx.x & 31;      // 128 rows per block
    int t = threadIdx.x;
    const float4* qg = (const float4*)(qk + (size_t)b * H * C);
    for (int i = t; i < H * 192; i += 512) qks[i] = qg[i];
    __syncthreads();
    int wave = t >> 6, lane = t & 63;
    int n0 = chunk * 128 + wave * 16;  // 16 rows per wave, 8 pairs
    const float4* xbase = (const float4*)(x + (size_t)b * N * C);
    float4 Xc[2][3], Xn[2][3];
#pragma unroll
    for (int r = 0; r < 2; ++r)
#pragma unroll
        for (int j = 0; j < 3; ++j)
            Xc[r][j] = xbase[(size_t)(n0 + r) * 192 + j * 64 + lane];
    for (int pr = 0; pr < 8; ++pr) {
        int n = n0 + pr * 2;
        if (pr < 7) {
#pragma unroll
            for (int r = 0; r < 2; ++r)
#pragma unroll
                for (int j = 0; j < 3; ++j)
                    Xn[r][j] = xbase[(size_t)(n + 2 + r) * 192 + j * 64 + lane];
        }
        float s0[H], s1[H];
#pragma unroll
        for (int h = 0; h < H; ++h) {
            float4 a0 = qks[h * 192 + lane];
            float4 a1 = qks[h * 192 + 64 + lane];
            float4 a2 = qks[h * 192 + 128 + lane];
            float u = Xc[0][0].x * a0.x;
            u = fmaf(Xc[0][0].y, a0.y, u); u = fmaf(Xc[0][0].z, a0.z, u); u = fmaf(Xc[0][0].w, a0.w, u);
            u = fmaf(Xc[0][1].x, a1.x, u); u = fmaf(Xc[0][1].y, a1.y, u);
            u = fmaf(Xc[0][1].z, a1.z, u); u = fmaf(Xc[0][1].w, a1.w, u);
            u = fmaf(Xc[0][2].x, a2.x, u); u = fmaf(Xc[0][2].y, a2.y, u);
            u = fmaf(Xc[0][2].z, a2.z, u); u = fmaf(Xc[0][2].w, a2.w, u);
            s0[h] = u;
            float v = Xc[1][0].x * a0.x;
            v = fmaf(Xc[1][0].y, a0.y, v); v = fmaf(Xc[1][0].z, a0.z, v); v = fmaf(Xc[1][0].w, a0.w, v);
            v = fmaf(Xc[1][1].x, a1.x, v); v = fmaf(Xc[1][1].y, a1.y, v);
            v = fmaf(Xc[1][1].z, a1.z, v); v = fmaf(Xc[1][1].w, a1.w, v);
            v = fmaf(Xc[1][2].x, a2.x, v); v = fmaf(Xc[1][2].y, a2.y, v);
            v = fmaf(Xc[1][2].z, a2.z, v); v = fmaf(Xc[1][2].w, a2.w, v);
            s1[h] = v;
        }
#pragma unroll
        for (int h = 0; h < H; ++h) {
            float u = s0[h], v = s1[h];
            for (int off = 32; off; off >>= 1) {
                u += __shfl_xor(u, off);
                v += __shfl_xor(v, off);
            }
            s0[h] = u; s1[h] = v;
        }
        float o0 = 0.f, o1 = 0.f;
#pragma unroll
        for (int h = 0; h < H; ++h)
            if (lane == h) { o0 = s0[h]; o1 = s1[h]; }
        if (lane < H) {
            p2[((size_t)b * H + lane) * N + n]     = o0;
            p2[((size_t)b * H + lane) * N + n + 1] = o1;
        }
#pragma unroll
        for (int r = 0; r < 2; ++r)
#pragma unroll
            for (int j = 0; j < 3; ++j)
                Xc[r][j] = Xn[r][j];
    }
}

// K4: softmax over n for each (b,h); p2 is [B,H,N] — fully coalesced
__global__ __launch_bounds__(256) void k4_softmax(float* __restrict__ p2) {
    int t = threadIdx.x;
    float4* pr = (float4*)(p2 + (size_t)blockIdx.x * N);
    float4 v[4];
    float m = -1e30f;
#pragma unroll
    for (int i = 0; i < 4; ++i) {
        v[i] = pr[t + i * 256];
        m = fmaxf(m, fmaxf(fmaxf(v[i].x, v[i].y), fmaxf(v[i].z, v[i].w)));
    }
    __shared__ float red[4], red2[4];
    for (int off = 32; off; off >>= 1) m = fmaxf(m, __shfl_xor(m, off));
    if ((t & 63) == 0) red[t >> 6] = m;
    __syncthreads();
    m = fmaxf(fmaxf(red[0], red[1]), fmaxf(red[2], red[3]));
    float s = 0.f;
#pragma unroll
    for (int i = 0; i < 4; ++i) {
        v[i].x = __expf(v[i].x - m); v[i].y = __expf(v[i].y - m);
        v[i].z = __expf(v[i].z - m); v[i].w = __expf(v[i].w - m);
        s += v[i].x + v[i].y + v[i].z + v[i].w;
    }
    for (int off = 32; off; off >>= 1) s += __shfl_xor(s, off);
    if ((t & 63) == 0) red2[t >> 6] = s;
    __syncthreads();
    s = red2[0] + red2[1] + red2[2] + red2[3];
    float inv = 1.f / s;
#pragma unroll
    for (int i = 0; i < 4; ++i) {
        v[i].x *= inv; v[i].y *= inv; v[i].z *= inv; v[i].w *= inv;
        pr[t + i * 256] = v[i];
    }
}

// K5: xa[b,h,c] += sum_n p2[b,h,n] * x[b,n,c]; x read once, float4, 3-deep prefetch
__global__ __launch_bounds__(192) void k5_xa(const float* __restrict__ x,
                                             const float* __restrict__ p2,
                                             float* __restrict__ xa) {
    __shared__ float ps[H][128];
    int b = blockIdx.x >> 5, ns = blockIdx.x & 31;
    int n0 = ns * 128;
    int t = threadIdx.x;
    for (int i = t; i < H * 128; i += 192) {
        int h = i >> 7, j = i & 127;
        ps[h][j] = p2[((size_t)b * H + h) * N + n0 + j];
    }
    __syncthreads();
    const float4* xr = (const float4*)(x + ((size_t)b * N + n0) * C);
    float4 acc[H];
#pragma unroll
    for (int h = 0; h < H; ++h) acc[h] = make_float4(0.f, 0.f, 0.f, 0.f);
    float4 x0 = xr[t], x1 = xr[192 + t], x2 = xr[384 + t];
    for (int r = 0; r < 128; ++r) {
        float4 cur = x0;
        x0 = x1; x1 = x2;
        int rn = (r + 3 < 128) ? (r + 3) : r;
        x2 = xr[rn * 192 + t];
#pragma unroll
        for (int h = 0; h < H; ++h) {
            float pv = ps[h][r];
            acc[h].x = fmaf(pv, cur.x, acc[h].x);
            acc[h].y = fmaf(pv, cur.y, acc[h].y);
            acc[h].z = fmaf(pv, cur.z, acc[h].z);
            acc[h].w = fmaf(pv, cur.w, acc[h].w);
        }
    }
#pragma unroll
    for (int h = 0; h < H; ++h) {
        float* dst = xa + ((size_t)b * H + h) * C + 4 * t;
        atomicAdd(dst + 0, acc[h].x);
        atomicAdd(dst + 1, acc[h].y);
        atomicAdd(dst + 2, acc[h].z);
        atomicAdd(dst + 3, acc[h].w);
    }
}

// K6: o[b, h*64+d] = sum_c xa[b,h,c] * Wv[c, h*64+d]
__global__ __launch_bounds__(256) void k6_o(const float* __restrict__ xa,
                                            const float* __restrict__ Wv,
                                            float* __restrict__ o) {
    int id = blockIdx.x * 256 + threadIdx.x;   // B*C
    int b = id / C;
    int r = id % C;
    int h = r / HD;
    const float* xr = xa + ((size_t)b * H + h) * C;
    const float* wcol = Wv + r;
    float acc = 0.f;
    for (int c = 0; c < C; ++c) acc = fmaf(xr[c], wcol[(size_t)c * C], acc);
    o[id] = acc;
}

// K7: out[b,co] = bp[co] + sum_c o[b,c] * Wp[c,co]
__global__ __launch_bounds__(256) void k7_out(const float* __restrict__ o,
                                              const float* __restrict__ Wp,
                                              const float* __restrict__ bp,
                                              float* __restrict__ out) {
    int id = blockIdx.x * 256 + threadIdx.x;
    int b = id / C;
    int co = id % C;
    const float* orow = o + (size_t)b * C;
    float acc = bp[co];
    for (int c = 0; c < C; ++c) acc = fmaf(orow[c], Wp[(size_t)c * C + co], acc);
    out[id] = acc;
}

extern "C" void kernel_launch(void* const* d_in, const int* in_sizes, int n_in,
                              void* d_out, int out_size, void* d_ws, size_t ws_size,
                              hipStream_t stream) {
    const float* x  = (const float*)d_in[0];
    const float* Wq = (const float*)d_in[1];
    const float* Wk = (const float*)d_in[2];
    const float* Wv = (const float*)d_in[3];
    const float* Wp = (const float*)d_in[4];
    const float* bp = (const float*)d_in[5];
    float* out = (float*)d_out;

    float* ws  = (float*)d_ws;
    float* q   = ws;                          // B*C       = 24576
    float* qk  = q + B * C;                   // B*H*C     = 294912
    float* p2  = qk + (size_t)B * H * C;      // B*H*N     = 1572864
    float* xa  = p2 + (size_t)B * H * N;      // B*H*C     = 294912
    float* o   = xa + (size_t)B * H * C;      // B*C       = 24576
    float* WkT = o + B * C;                   // C*C       = 589824

    kT        <<<576,  256, 0, stream>>>(Wk, WkT);
    k1_q      <<<96,   256, 0, stream>>>(x, Wq, q);
    k2_qk     <<<384,  256, 0, stream>>>(q, WkT, qk, xa);
    k3_scores <<<1024, 512, 0, stream>>>(x, qk, p2);
    k4_softmax<<<384,  256, 0, stream>>>(p2);
    k5_xa     <<<1024, 192, 0, stream>>>(x, p2, xa);
    k6_o      <<<96,   256, 0, stream>>>(xa, Wv, o);
    k7_out    <<<96,   256, 0, stream>>>(o, Wp, bp, out);
}

// Round 9
// 983.853 us; speedup vs baseline: 1.3415x; 1.3415x over previous
//
#include <hip/hip_runtime.h>
#include <hip/hip_bf16.h>

#define B 32
#define N 4096
#define C 768
#define H 12
#define HD 64
// SCALE = 0.125f folded into qk

// kT: WkT[co][c] = Wk[c][co]
__global__ __launch_bounds__(256) void kT(const float* __restrict__ A, float* __restrict__ AT) {
    __shared__ float tile[32][33];
    int bx = blockIdx.x % 24, by = blockIdx.x / 24;
    int tx = threadIdx.x & 31, ty = threadIdx.x >> 5;   // ty 0..7
#pragma unroll
    for (int i = 0; i < 32; i += 8)
        tile[ty + i][tx] = A[(size_t)(by * 32 + ty + i) * C + bx * 32 + tx];
    __syncthreads();
#pragma unroll
    for (int i = 0; i < 32; i += 8)
        AT[(size_t)(bx * 32 + ty + i) * C + by * 32 + tx] = tile[tx][ty + i];
}

// K1: q[b,co] = sum_c x[b,0,c] * Wq[c,co]
__global__ __launch_bounds__(256) void k1_q(const float* __restrict__ x,
                                            const float* __restrict__ Wq,
                                            float* __restrict__ q) {
    __shared__ float xs[C];
    int b = blockIdx.x / 3;
    int coBase = (blockIdx.x % 3) * 256;
    int t = threadIdx.x;
    for (int i = t; i < C; i += 256) xs[i] = x[(size_t)b * N * C + i];
    __syncthreads();
    int co = coBase + t;
    float acc = 0.f;
    for (int c = 0; c < C; ++c) acc = fmaf(xs[c], Wq[(size_t)c * C + co], acc);
    q[b * C + co] = acc;
}

// K2: qk[b,h,c] = 0.125 * sum_d q[b,h*64+d] * WkT[h*64+d, c]; also zero xa
__global__ __launch_bounds__(256) void k2_qk(const float* __restrict__ q,
                                             const float* __restrict__ WkT,
                                             float* __restrict__ qk,
                                             float* __restrict__ xa) {
    int b = blockIdx.x / H, h = blockIdx.x % H;
    int t = threadIdx.x;
    __shared__ float qs[HD];
    if (t < HD) qs[t] = q[b * C + h * HD + t];
    float* xab = xa + ((size_t)b * H + h) * C;
    xab[t] = 0.f; xab[t + 256] = 0.f; xab[t + 512] = 0.f;
    __syncthreads();
    float a0 = 0.f, a1 = 0.f, a2 = 0.f;
    const float* wbase = WkT + (size_t)h * HD * C;
    for (int d = 0; d < HD; ++d) {
        float qd = qs[d];
        const float* wr = wbase + (size_t)d * C;
        a0 = fmaf(qd, wr[t], a0);
        a1 = fmaf(qd, wr[t + 256], a1);
        a2 = fmaf(qd, wr[t + 512], a2);
    }
    float* qkb = qk + ((size_t)b * H + h) * C;
    qkb[t] = a0 * 0.125f; qkb[t + 256] = a1 * 0.125f; qkb[t + 512] = a2 * 0.125f;
}

// K3: p2[b,h,n] = x[b,n,:] . qk[b,h,:]  — 256 thr / 64 rows / LDS-staged coalesced output
__global__ __launch_bounds__(256) void k3_scores(const float* __restrict__ x,
                                                 const float* __restrict__ qk,
                                                 float* __restrict__ p2) {
    __shared__ float4 qks[H * 192];   // 36 KB
    __shared__ float ss[H * 66];      // padded score tile (stride 66 kills bank conflicts)
    int b = blockIdx.x >> 6;
    int chunk = blockIdx.x & 63;      // 64 rows per block
    int t = threadIdx.x;
    const float4* qg = (const float4*)(qk + (size_t)b * H * C);
    for (int i = t; i < H * 192; i += 256) qks[i] = qg[i];
    __syncthreads();
    int wave = t >> 6, lane = t & 63;
    int r0 = wave * 16;               // row offset within block's 64 (4 waves x 16 rows)
    int n0 = chunk * 64 + r0;
    const float4* xbase = (const float4*)(x + (size_t)b * N * C);
    float4 Xc[2][3], Xn[2][3];
#pragma unroll
    for (int r = 0; r < 2; ++r)
#pragma unroll
        for (int j = 0; j < 3; ++j)
            Xc[r][j] = xbase[(size_t)(n0 + r) * 192 + j * 64 + lane];
    for (int pr = 0; pr < 8; ++pr) {
        if (pr < 7) {
#pragma unroll
            for (int r = 0; r < 2; ++r)
#pragma unroll
                for (int j = 0; j < 3; ++j)
                    Xn[r][j] = xbase[(size_t)(n0 + pr * 2 + 2 + r) * 192 + j * 64 + lane];
        }
        float s0[H], s1[H];
#pragma unroll
        for (int h = 0; h < H; ++h) {
            float4 a0 = qks[h * 192 + lane];
            float4 a1 = qks[h * 192 + 64 + lane];
            float4 a2 = qks[h * 192 + 128 + lane];
            float u = Xc[0][0].x * a0.x;
            u = fmaf(Xc[0][0].y, a0.y, u); u = fmaf(Xc[0][0].z, a0.z, u); u = fmaf(Xc[0][0].w, a0.w, u);
            u = fmaf(Xc[0][1].x, a1.x, u); u = fmaf(Xc[0][1].y, a1.y, u);
            u = fmaf(Xc[0][1].z, a1.z, u); u = fmaf(Xc[0][1].w, a1.w, u);
            u = fmaf(Xc[0][2].x, a2.x, u); u = fmaf(Xc[0][2].y, a2.y, u);
            u = fmaf(Xc[0][2].z, a2.z, u); u = fmaf(Xc[0][2].w, a2.w, u);
            s0[h] = u;
            float v = Xc[1][0].x * a0.x;
            v = fmaf(Xc[1][0].y, a0.y, v); v = fmaf(Xc[1][0].z, a0.z, v); v = fmaf(Xc[1][0].w, a0.w, v);
            v = fmaf(Xc[1][1].x, a1.x, v); v = fmaf(Xc[1][1].y, a1.y, v);
            v = fmaf(Xc[1][1].z, a1.z, v); v = fmaf(Xc[1][1].w, a1.w, v);
            v = fmaf(Xc[1][2].x, a2.x, v); v = fmaf(Xc[1][2].y, a2.y, v);
            v = fmaf(Xc[1][2].z, a2.z, v); v = fmaf(Xc[1][2].w, a2.w, v);
            s1[h] = v;
        }
#pragma unroll
        for (int h = 0; h < H; ++h) {
            float u = s0[h], v = s1[h];
            for (int off = 32; off; off >>= 1) {
                u += __shfl_xor(u, off);
                v += __shfl_xor(v, off);
            }
            s0[h] = u; s1[h] = v;
        }
        float o0 = 0.f, o1 = 0.f;
#pragma unroll
        for (int h = 0; h < H; ++h)
            if (lane == h) { o0 = s0[h]; o1 = s1[h]; }
        if (lane < H) {
            int row = r0 + pr * 2;
            ss[lane * 66 + row]     = o0;
            ss[lane * 66 + row + 1] = o1;
        }
#pragma unroll
        for (int r = 0; r < 2; ++r)
#pragma unroll
            for (int j = 0; j < 3; ++j)
                Xc[r][j] = Xn[r][j];
    }
    __syncthreads();
    // coalesced epilogue: each head's 64 consecutive n written as dense 256-B runs
    for (int i = t; i < H * 64; i += 256) {
        int h = i >> 6, j = i & 63;
        p2[((size_t)b * H + h) * N + chunk * 64 + j] = ss[h * 66 + j];
    }
}

// K4: softmax over n for each (b,h); p2 is [B,H,N] — fully coalesced
__global__ __launch_bounds__(256) void k4_softmax(float* __restrict__ p2) {
    int t = threadIdx.x;
    float4* pr = (float4*)(p2 + (size_t)blockIdx.x * N);
    float4 v[4];
    float m = -1e30f;
#pragma unroll
    for (int i = 0; i < 4; ++i) {
        v[i] = pr[t + i * 256];
        m = fmaxf(m, fmaxf(fmaxf(v[i].x, v[i].y), fmaxf(v[i].z, v[i].w)));
    }
    __shared__ float red[4], red2[4];
    for (int off = 32; off; off >>= 1) m = fmaxf(m, __shfl_xor(m, off));
    if ((t & 63) == 0) red[t >> 6] = m;
    __syncthreads();
    m = fmaxf(fmaxf(red[0], red[1]), fmaxf(red[2], red[3]));
    float s = 0.f;
#pragma unroll
    for (int i = 0; i < 4; ++i) {
        v[i].x = __expf(v[i].x - m); v[i].y = __expf(v[i].y - m);
        v[i].z = __expf(v[i].z - m); v[i].w = __expf(v[i].w - m);
        s += v[i].x + v[i].y + v[i].z + v[i].w;
    }
    for (int off = 32; off; off >>= 1) s += __shfl_xor(s, off);
    if ((t & 63) == 0) red2[t >> 6] = s;
    __syncthreads();
    s = red2[0] + red2[1] + red2[2] + red2[3];
    float inv = 1.f / s;
#pragma unroll
    for (int i = 0; i < 4; ++i) {
        v[i].x *= inv; v[i].y *= inv; v[i].z *= inv; v[i].w *= inv;
        pr[t + i * 256] = v[i];
    }
}

// K5: xa[b,h,c] += sum_n p2[b,h,n] * x[b,n,c]; x read once, float4, 3-deep prefetch
__global__ __launch_bounds__(192) void k5_xa(const float* __restrict__ x,
                                             const float* __restrict__ p2,
                                             float* __restrict__ xa) {
    __shared__ float ps[H][128];
    int b = blockIdx.x >> 5, ns = blockIdx.x & 31;
    int n0 = ns * 128;
    int t = threadIdx.x;
    for (int i = t; i < H * 128; i += 192) {
        int h = i >> 7, j = i & 127;
        ps[h][j] = p2[((size_t)b * H + h) * N + n0 + j];
    }
    __syncthreads();
    const float4* xr = (const float4*)(x + ((size_t)b * N + n0) * C);
    float4 acc[H];
#pragma unroll
    for (int h = 0; h < H; ++h) acc[h] = make_float4(0.f, 0.f, 0.f, 0.f);
    float4 x0 = xr[t], x1 = xr[192 + t], x2 = xr[384 + t];
    for (int r = 0; r < 128; ++r) {
        float4 cur = x0;
        x0 = x1; x1 = x2;
        int rn = (r + 3 < 128) ? (r + 3) : r;
        x2 = xr[rn * 192 + t];
#pragma unroll
        for (int h = 0; h < H; ++h) {
            float pv = ps[h][r];
            acc[h].x = fmaf(pv, cur.x, acc[h].x);
            acc[h].y = fmaf(pv, cur.y, acc[h].y);
            acc[h].z = fmaf(pv, cur.z, acc[h].z);
            acc[h].w = fmaf(pv, cur.w, acc[h].w);
        }
    }
#pragma unroll
    for (int h = 0; h < H; ++h) {
        float* dst = xa + ((size_t)b * H + h) * C + 4 * t;
        atomicAdd(dst + 0, acc[h].x);
        atomicAdd(dst + 1, acc[h].y);
        atomicAdd(dst + 2, acc[h].z);
        atomicAdd(dst + 3, acc[h].w);
    }
}

// K6: o[b, h*64+d] = sum_c xa[b,h,c] * Wv[c, h*64+d]
__global__ __launch_bounds__(256) void k6_o(const float* __restrict__ xa,
                                            const float* __restrict__ Wv,
                                            float* __restrict__ o) {
    int id = blockIdx.x * 256 + threadIdx.x;   // B*C
    int b = id / C;
    int r = id % C;
    int h = r / HD;
    const float* xr = xa + ((size_t)b * H + h) * C;
    const float* wcol = Wv + r;
    float acc = 0.f;
    for (int c = 0; c < C; ++c) acc = fmaf(xr[c], wcol[(size_t)c * C], acc);
    o[id] = acc;
}

// K7: out[b,co] = bp[co] + sum_c o[b,c] * Wp[c,co]
__global__ __launch_bounds__(256) void k7_out(const float* __restrict__ o,
                                              const float* __restrict__ Wp,
                                              const float* __restrict__ bp,
                                              float* __restrict__ out) {
    int id = blockIdx.x * 256 + threadIdx.x;
    int b = id / C;
    int co = id % C;
    const float* orow = o + (size_t)b * C;
    float acc = bp[co];
    for (int c = 0; c < C; ++c) acc = fmaf(orow[c], Wp[(size_t)c * C + co], acc);
    out[id] = acc;
}

extern "C" void kernel_launch(void* const* d_in, const int* in_sizes, int n_in,
                              void* d_out, int out_size, void* d_ws, size_t ws_size,
                              hipStream_t stream) {
    const float* x  = (const float*)d_in[0];
    const float* Wq = (const float*)d_in[1];
    const float* Wk = (const float*)d_in[2];
    const float* Wv = (const float*)d_in[3];
    const float* Wp = (const float*)d_in[4];
    const float* bp = (const float*)d_in[5];
    float* out = (float*)d_out;

    float* ws  = (float*)d_ws;
    float* q   = ws;                          // B*C       = 24576
    float* qk  = q + B * C;                   // B*H*C     = 294912
    float* p2  = qk + (size_t)B * H * C;      // B*H*N     = 1572864
    float* xa  = p2 + (size_t)B * H * N;      // B*H*C     = 294912
    float* o   = xa + (size_t)B * H * C;      // B*C       = 24576
    float* WkT = o + B * C;                   // C*C       = 589824

    kT        <<<576,  256, 0, stream>>>(Wk, WkT);
    k1_q      <<<96,   256, 0, stream>>>(x, Wq, q);
    k2_qk     <<<384,  256, 0, stream>>>(q, WkT, qk, xa);
    k3_scores <<<2048, 256, 0, stream>>>(x, qk, p2);
    k4_softmax<<<384,  256, 0, stream>>>(p2);
    k5_xa     <<<1024, 192, 0, stream>>>(x, p2, xa);
    k6_o      <<<96,   256, 0, stream>>>(xa, Wv, o);
    k7_out    <<<96,   256, 0, stream>>>(o, Wp, bp, out);
}